// Round 1
// baseline (2459.608 us; speedup 1.0000x reference)
//
#include <hip/hip_runtime.h>

// ---------------------------------------------------------------------------
// LMAR model, fp32 correctness-first implementation.
// B=2, C=3, H=W=512, down=256. Output tuple (flat concat):
//   down_x_mod (2,3,256,256) | hr_feature (2,64,256,256) |
//   new_lr_feature (2,64,256,256) | ori_lr_feature (2,64,256,256) | out (2,3,256,256)
// ---------------------------------------------------------------------------

// ---- bicubic (Keys a=-0.5) tap helpers, matching jax.image.resize
// (method='bicubic', antialias=False) with per-column weight renormalization.

__device__ __forceinline__ void down_taps(int o, int n, int t[4], float w[4]) {
  // 2x downscale: sample coord u = 2o + 0.5; taps 2o-1 .. 2o+2
  const float ww0 = -0.0625f, ww1 = 0.5625f;
  float wfull[4] = {ww0, ww1, ww1, ww0};
  float s = 0.f;
#pragma unroll
  for (int d = 0; d < 4; ++d) {
    int tt = 2 * o - 1 + d;
    bool v = (tt >= 0) && (tt < n);
    t[d] = v ? tt : 0;
    w[d] = v ? wfull[d] : 0.f;
    s += w[d];
  }
#pragma unroll
  for (int d = 0; d < 4; ++d) w[d] = w[d] / s;
}

__device__ __forceinline__ void up_taps(int o, int n, int t[4], float w[4]) {
  // 2x upscale: u = 0.5*o - 0.25
  int m = o >> 1;
  float wfull[4];
  int base;
  if ((o & 1) == 0) {
    base = m - 2;
    wfull[0] = -0.0234375f; wfull[1] = 0.2265625f;
    wfull[2] = 0.8671875f;  wfull[3] = -0.0703125f;
  } else {
    base = m - 1;
    wfull[0] = -0.0703125f; wfull[1] = 0.8671875f;
    wfull[2] = 0.2265625f;  wfull[3] = -0.0234375f;
  }
  float s = 0.f;
#pragma unroll
  for (int d = 0; d < 4; ++d) {
    int tt = base + d;
    bool v = (tt >= 0) && (tt < n);
    t[d] = v ? tt : 0;
    w[d] = v ? wfull[d] : 0.f;
    s += w[d];
  }
#pragma unroll
  for (int d = 0; d < 4; ++d) w[d] = w[d] / s;
}

// ---- generic 2x bicubic downscale: src (Ct, inH, inW) -> dst (Ct, inH/2, inW/2)
__global__ __launch_bounds__(256) void down2_k(const float* __restrict__ src,
                                               float* __restrict__ dst,
                                               int Ct, int inH, int inW) {
  int oH = inH >> 1, oW = inW >> 1;
  int idx = blockIdx.x * 256 + threadIdx.x;
  int total = Ct * oH * oW;
  if (idx >= total) return;
  int ox = idx % oW;
  int r = idx / oW;
  int oy = r % oH;
  int c = r / oH;
  int ty[4], tx[4];
  float wy[4], wx[4];
  down_taps(oy, inH, ty, wy);
  down_taps(ox, inW, tx, wx);
  const float* s = src + (size_t)c * inH * inW;
  float acc = 0.f;
#pragma unroll
  for (int a = 0; a < 4; ++a) {
    float row = 0.f;
#pragma unroll
    for (int b = 0; b < 4; ++b) row += wx[b] * s[(size_t)ty[a] * inW + tx[b]];
    acc += wy[a] * row;
  }
  dst[idx] = acc;
}

// ---- generic 2x bicubic upscale: src (Ct, inH, inW) -> dst (Ct, 2*inH, 2*inW)
__global__ __launch_bounds__(256) void up2_k(const float* __restrict__ src,
                                             float* __restrict__ dst,
                                             int Ct, int inH, int inW) {
  int oH = inH * 2, oW = inW * 2;
  int idx = blockIdx.x * 256 + threadIdx.x;
  int total = Ct * oH * oW;
  if (idx >= total) return;
  int ox = idx % oW;
  int r = idx / oW;
  int oy = r % oH;
  int c = r / oH;
  int ty[4], tx[4];
  float wy[4], wx[4];
  up_taps(oy, inH, ty, wy);
  up_taps(ox, inW, tx, wx);
  const float* s = src + (size_t)c * inH * inW;
  float acc = 0.f;
#pragma unroll
  for (int a = 0; a < 4; ++a) {
    float row = 0.f;
#pragma unroll
    for (int b = 0; b < 4; ++b) row += wx[b] * s[(size_t)ty[a] * inW + tx[b]];
    acc += wy[a] * row;
  }
  dst[idx] = acc;
}

// ---- laplacian: lap = x - upscale2(down_x); x,lap (6,512,512), down_x (6,256,256)
__global__ __launch_bounds__(256) void lap_k(const float* __restrict__ x,
                                             const float* __restrict__ down_x,
                                             float* __restrict__ lap) {
  int idx = blockIdx.x * 256 + threadIdx.x;
  if (idx >= 6 * 512 * 512) return;
  int ox = idx & 511;
  int r = idx >> 9;
  int oy = r & 511;
  int c = r >> 9;
  int ty[4], tx[4];
  float wy[4], wx[4];
  up_taps(oy, 256, ty, wy);
  up_taps(ox, 256, tx, wx);
  const float* s = down_x + (size_t)c * 256 * 256;
  float acc = 0.f;
#pragma unroll
  for (int a = 0; a < 4; ++a) {
    float row = 0.f;
#pragma unroll
    for (int b = 0; b < 4; ++b) row += wx[b] * s[ty[a] * 256 + tx[b]];
    acc += wy[a] * row;
  }
  lap[idx] = x[idx] - acc;
}

// ---- conv 3x3 stride2 pad1: src (2,3,inH,inW) -> dst (2,64,inH/2,inW/2)
__global__ __launch_bounds__(256) void conv3s2_k(const float* __restrict__ src,
                                                 const float* __restrict__ w,
                                                 const float* __restrict__ bias,
                                                 float* __restrict__ dst,
                                                 int inH, int inW) {
  int oH = inH >> 1, oW = inW >> 1;
  int idx = blockIdx.x * 256 + threadIdx.x;
  int total = 2 * 64 * oH * oW;
  if (idx >= total) return;
  int ox = idx % oW;
  int t = idx / oW;
  int oy = t % oH;
  t /= oH;
  int co = t & 63;
  int b = t >> 6;
  const float* sb = src + (size_t)b * 3 * inH * inW;
  const float* wc = w + co * 27;
  float acc = bias[co];
#pragma unroll
  for (int ci = 0; ci < 3; ++ci) {
    const float* sc = sb + (size_t)ci * inH * inW;
#pragma unroll
    for (int ky = 0; ky < 3; ++ky) {
      int iy = 2 * oy - 1 + ky;
      if (iy < 0 || iy >= inH) continue;
#pragma unroll
      for (int kx = 0; kx < 3; ++kx) {
        int ix = 2 * ox - 1 + kx;
        if (ix < 0 || ix >= inW) continue;
        acc += wc[ci * 9 + ky * 3 + kx] * sc[(size_t)iy * inW + ix];
      }
    }
  }
  dst[idx] = acc;
}

// ---- 1x1 conv: cat(down_x(2,3,256,256), outd(2,3,256,256)) * mod_w(3,6) + mod_b
__global__ __launch_bounds__(256) void modconv_k(const float* __restrict__ down_x,
                                                 const float* __restrict__ outd,
                                                 const float* __restrict__ mw,
                                                 const float* __restrict__ mb,
                                                 float* __restrict__ dst) {
  int idx = blockIdx.x * 256 + threadIdx.x;
  if (idx >= 2 * 3 * 65536) return;
  int p = idx & 65535;
  int r = idx >> 16;
  int co = r % 3;
  int b = r / 3;
  const float* dxb = down_x + (size_t)b * 3 * 65536;
  const float* ob = outd + (size_t)b * 3 * 65536;
  float acc = mb[co];
#pragma unroll
  for (int ci = 0; ci < 3; ++ci) acc += mw[co * 6 + ci] * dxb[ci * 65536 + p];
#pragma unroll
  for (int ci = 0; ci < 3; ++ci) acc += mw[co * 6 + 3 + ci] * ob[ci * 65536 + p];
  dst[idx] = acc;
}

// ---------------------------------------------------------------------------
// Fused MLP (7->128->128->128->128->128->81, leaky_relu 0.01) + einsum with
// 3x3 unfolded patches of x. One block = 128 pixels, 256 threads.
// h buffers in LDS, layout [k][px] (transposed), W staged 32 rows at a time.
// Thread tile: 8 px x 8 n (tx = tid&15 -> n0=tx*8, ty = tid>>4 -> px0=ty*8).
// ---------------------------------------------------------------------------
#define MLP_PX 128

__device__ __forceinline__ void run_layer(const float (*hIn)[128],
                                          float (*hOut)[128],
                                          float (*Wl)[128],
                                          const float* __restrict__ Wg,
                                          int K, int Ncols, bool leaky,
                                          int tid) {
  const int tx = tid & 15;
  const int ty = tid >> 4;
  const int n0 = tx * 8;
  const int px0 = ty * 8;

  float acc[8][8];
#pragma unroll
  for (int pp = 0; pp < 8; ++pp)
#pragma unroll
    for (int nn = 0; nn < 8; ++nn) acc[pp][nn] = 0.f;

  for (int ks = 0; ks < K; ks += 32) {
    int rows = (K - ks) < 32 ? (K - ks) : 32;
    __syncthreads();  // everyone done with previous Wl contents
    for (int t = tid; t < 32 * 128; t += 256) {
      int kk = t >> 7;
      int n = t & 127;
      float v = 0.f;
      if (kk < rows && n < Ncols) v = Wg[(size_t)(ks + kk) * Ncols + n];
      Wl[kk][n] = v;
    }
    __syncthreads();
#pragma unroll 4
    for (int kk = 0; kk < rows; ++kk) {
      float4 a0 = *(const float4*)&hIn[ks + kk][px0];
      float4 a1 = *(const float4*)&hIn[ks + kk][px0 + 4];
      float4 b0 = *(const float4*)&Wl[kk][n0];
      float4 b1 = *(const float4*)&Wl[kk][n0 + 4];
      float a[8] = {a0.x, a0.y, a0.z, a0.w, a1.x, a1.y, a1.z, a1.w};
      float bb[8] = {b0.x, b0.y, b0.z, b0.w, b1.x, b1.y, b1.z, b1.w};
#pragma unroll
      for (int pp = 0; pp < 8; ++pp)
#pragma unroll
        for (int nn = 0; nn < 8; ++nn) acc[pp][nn] += a[pp] * bb[nn];
    }
  }
  // write transposed: hOut[n][px]
#pragma unroll
  for (int nn = 0; nn < 8; ++nn) {
    float v[8];
#pragma unroll
    for (int pp = 0; pp < 8; ++pp) {
      float t = acc[pp][nn];
      v[pp] = leaky ? (t > 0.f ? t : 0.01f * t) : t;
    }
    *(float4*)&hOut[n0 + nn][px0] = make_float4(v[0], v[1], v[2], v[3]);
    *(float4*)&hOut[n0 + nn][px0 + 4] = make_float4(v[4], v[5], v[6], v[7]);
  }
  __syncthreads();
}

__global__ __launch_bounds__(256) void mlp_einsum_k(
    const float* __restrict__ x, const float* __restrict__ lap,
    const float* __restrict__ Win, const float* __restrict__ Wh1,
    const float* __restrict__ Wh2, const float* __restrict__ Wh3,
    const float* __restrict__ Wh4, const float* __restrict__ Wout,
    float* __restrict__ out_full) {
  __shared__ float hA[128][128];
  __shared__ float hB[128][128];
  __shared__ float Wl[32][128];

  const int tid = threadIdx.x;
  const int pbase = blockIdx.x * MLP_PX;

  // build MLP input into hA[k][px], k = 0..6:
  // [rel_y(+-0.5), rel_x(+-0.5), 1, 1, lap0, lap1, lap2]
  if (tid < MLP_PX) {
    int px = tid;
    int p = pbase + px;
    int b = p >> 18;           // 262144 px per batch image
    int rem = p & 262143;
    int i = rem >> 9;
    int j = rem & 511;
    hA[0][px] = (i & 1) ? 0.5f : -0.5f;
    hA[1][px] = (j & 1) ? 0.5f : -0.5f;
    hA[2][px] = 1.0f;
    hA[3][px] = 1.0f;
    const float* lp = lap + (size_t)b * 3 * 262144 + rem;
    hA[4][px] = lp[0];
    hA[5][px] = lp[262144];
    hA[6][px] = lp[2 * 262144];
  }
  __syncthreads();

  run_layer(hA, hB, Wl, Win, 7, 128, true, tid);
  run_layer(hB, hA, Wl, Wh1, 128, 128, true, tid);
  run_layer(hA, hB, Wl, Wh2, 128, 128, true, tid);
  run_layer(hB, hA, Wl, Wh3, 128, 128, true, tid);
  run_layer(hA, hB, Wl, Wh4, 128, 128, true, tid);
  run_layer(hB, hA, Wl, Wout, 128, 81, false, tid);
  // local_weight (81 per pixel) now in hA[n][px], n = 0..80

  // einsum: out[co] = sum_{c,ki,kj} x[b,c,i+ki-1,j+kj-1] * lw[(c*9+ki*3+kj)*3+co]
  if (tid < MLP_PX) {
    int px = tid;
    int p = pbase + px;
    int b = p >> 18;
    int rem = p & 262143;
    int i = rem >> 9;
    int j = rem & 511;
    const float* xb = x + (size_t)b * 3 * 262144;
    float o0 = 0.f, o1 = 0.f, o2 = 0.f;
#pragma unroll
    for (int c = 0; c < 3; ++c) {
      const float* xc = xb + (size_t)c * 262144;
#pragma unroll
      for (int ki = 0; ki < 3; ++ki) {
        int ii = i + ki - 1;
#pragma unroll
        for (int kj = 0; kj < 3; ++kj) {
          int jj = j + kj - 1;
          float pv = (ii >= 0 && ii < 512 && jj >= 0 && jj < 512)
                         ? xc[ii * 512 + jj]
                         : 0.f;
          int k3 = (c * 9 + ki * 3 + kj) * 3;
          o0 += pv * hA[k3][px];
          o1 += pv * hA[k3 + 1][px];
          o2 += pv * hA[k3 + 2][px];
        }
      }
    }
    float* ob = out_full + (size_t)b * 3 * 262144 + rem;
    ob[0] = o0;
    ob[262144] = o1;
    ob[2 * 262144] = o2;
  }
}

// ---------------------------------------------------------------------------
extern "C" void kernel_launch(void* const* d_in, const int* in_sizes, int n_in,
                              void* d_out, int out_size, void* d_ws,
                              size_t ws_size, hipStream_t stream) {
  const float* x = (const float*)d_in[0];
  const float* Win = (const float*)d_in[1];
  const float* Wh1 = (const float*)d_in[2];
  const float* Wh2 = (const float*)d_in[3];
  const float* Wh3 = (const float*)d_in[4];
  const float* Wh4 = (const float*)d_in[5];
  const float* Wout = (const float*)d_in[6];
  const float* fw = (const float*)d_in[7];
  const float* fb = (const float*)d_in[8];
  const float* mw = (const float*)d_in[9];
  const float* mb = (const float*)d_in[10];
  // d_in[11] = down_size(256), d_in[12] = up_size(512): fixed, hardcoded.

  // workspace layout (floats)
  float* ws = (float*)d_ws;
  float* down_x = ws;                    // 6*256*256      = 393216
  float* lap = ws + 393216;              // 6*512*512      = 1572864
  float* out_full = ws + 1966080;        // 6*512*512      = 1572864
  float* ctmp = ws + 3538944;            // 2*64*128*128   = 2097152 (reused)

  // output layout (floats)
  float* o_dxm = (float*)d_out;          // (2,3,256,256)  393216
  float* o_hr = o_dxm + 393216;          // (2,64,256,256) 8388608
  float* o_new = o_hr + 8388608;         // (2,64,256,256) 8388608
  float* o_ori = o_new + 8388608;        // (2,64,256,256) 8388608
  float* o_out = o_ori + 8388608;        // (2,3,256,256)  393216

  // 1. down_x = bicubic down2(x)
  down2_k<<<1536, 256, 0, stream>>>(x, down_x, 6, 512, 512);
  // 2. lap = x - up2(down_x)
  lap_k<<<6144, 256, 0, stream>>>(x, down_x, lap);
  // 3. MLP + einsum -> out_full (2,3,512,512)
  mlp_einsum_k<<<4096, 256, 0, stream>>>(x, lap, Win, Wh1, Wh2, Wh3, Wh4, Wout,
                                         out_full);
  // 4. out = down2(out_full)
  down2_k<<<1536, 256, 0, stream>>>(out_full, o_out, 6, 512, 512);
  // 5. down_x_mod = 1x1 conv(cat(down_x, out))
  modconv_k<<<1536, 256, 0, stream>>>(down_x, o_out, mw, mb, o_dxm);
  // 6. hr_feature = conv3x3 s2(x)
  conv3s2_k<<<32768, 256, 0, stream>>>(x, fw, fb, o_hr, 512, 512);
  // 7. ori_lr_feature = up2(conv3x3 s2(down_x))
  conv3s2_k<<<8192, 256, 0, stream>>>(down_x, fw, fb, ctmp, 256, 256);
  up2_k<<<32768, 256, 0, stream>>>(ctmp, o_ori, 128, 128, 128);
  // 8. new_lr_feature = up2(conv3x3 s2(down_x_mod))
  conv3s2_k<<<8192, 256, 0, stream>>>(o_dxm, fw, fb, ctmp, 256, 256);
  up2_k<<<32768, 256, 0, stream>>>(ctmp, o_new, 128, 128, 128);
}

// Round 2
// 655.738 us; speedup vs baseline: 3.7509x; 3.7509x over previous
//
#include <hip/hip_runtime.h>

// ---------------------------------------------------------------------------
// LMAR model. B=2, C=3, H=W=512, down=256. Output tuple (flat concat):
//   down_x_mod (2,3,256,256) | hr_feature (2,64,256,256) |
//   new_lr_feature (2,64,256,256) | ori_lr_feature (2,64,256,256) | out (2,3,256,256)
// MLP path: bf16 MFMA 16x16x32, activations hi/lo-split (fp32-exact),
// weights single bf16 pre-packed in fragment order.
// ---------------------------------------------------------------------------

typedef __attribute__((ext_vector_type(8))) short bf16x8;   // 8 bf16 = 4 VGPR
typedef __attribute__((ext_vector_type(4))) float f32x4;

__device__ __forceinline__ unsigned short f2bf(float f) {
  unsigned u = __float_as_uint(f);
  u = (u + 0x7fffu + ((u >> 16) & 1u)) >> 16;  // RNE
  return (unsigned short)u;
}
__device__ __forceinline__ float bf2f(unsigned short h) {
  return __uint_as_float(((unsigned)h) << 16);
}

// ---- bicubic (Keys a=-0.5) tap helpers, matching jax.image.resize
// (method='bicubic', antialias=False) with per-column weight renormalization.

__device__ __forceinline__ void down_taps(int o, int n, int t[4], float w[4]) {
  const float ww0 = -0.0625f, ww1 = 0.5625f;
  float wfull[4] = {ww0, ww1, ww1, ww0};
  float s = 0.f;
#pragma unroll
  for (int d = 0; d < 4; ++d) {
    int tt = 2 * o - 1 + d;
    bool v = (tt >= 0) && (tt < n);
    t[d] = v ? tt : 0;
    w[d] = v ? wfull[d] : 0.f;
    s += w[d];
  }
#pragma unroll
  for (int d = 0; d < 4; ++d) w[d] = w[d] / s;
}

__device__ __forceinline__ void up_taps(int o, int n, int t[4], float w[4]) {
  int m = o >> 1;
  float wfull[4];
  int base;
  if ((o & 1) == 0) {
    base = m - 2;
    wfull[0] = -0.0234375f; wfull[1] = 0.2265625f;
    wfull[2] = 0.8671875f;  wfull[3] = -0.0703125f;
  } else {
    base = m - 1;
    wfull[0] = -0.0703125f; wfull[1] = 0.8671875f;
    wfull[2] = 0.2265625f;  wfull[3] = -0.0234375f;
  }
  float s = 0.f;
#pragma unroll
  for (int d = 0; d < 4; ++d) {
    int tt = base + d;
    bool v = (tt >= 0) && (tt < n);
    t[d] = v ? tt : 0;
    w[d] = v ? wfull[d] : 0.f;
    s += w[d];
  }
#pragma unroll
  for (int d = 0; d < 4; ++d) w[d] = w[d] / s;
}

// ---- generic 2x bicubic downscale
__global__ __launch_bounds__(256) void down2_k(const float* __restrict__ src,
                                               float* __restrict__ dst,
                                               int Ct, int inH, int inW) {
  int oH = inH >> 1, oW = inW >> 1;
  int idx = blockIdx.x * 256 + threadIdx.x;
  int total = Ct * oH * oW;
  if (idx >= total) return;
  int ox = idx % oW;
  int r = idx / oW;
  int oy = r % oH;
  int c = r / oH;
  int ty[4], tx[4];
  float wy[4], wx[4];
  down_taps(oy, inH, ty, wy);
  down_taps(ox, inW, tx, wx);
  const float* s = src + (size_t)c * inH * inW;
  float acc = 0.f;
#pragma unroll
  for (int a = 0; a < 4; ++a) {
    float row = 0.f;
#pragma unroll
    for (int b = 0; b < 4; ++b) row += wx[b] * s[(size_t)ty[a] * inW + tx[b]];
    acc += wy[a] * row;
  }
  dst[idx] = acc;
}

// ---- generic 2x bicubic upscale
__global__ __launch_bounds__(256) void up2_k(const float* __restrict__ src,
                                             float* __restrict__ dst,
                                             int Ct, int inH, int inW) {
  int oH = inH * 2, oW = inW * 2;
  int idx = blockIdx.x * 256 + threadIdx.x;
  int total = Ct * oH * oW;
  if (idx >= total) return;
  int ox = idx % oW;
  int r = idx / oW;
  int oy = r % oH;
  int c = r / oH;
  int ty[4], tx[4];
  float wy[4], wx[4];
  up_taps(oy, inH, ty, wy);
  up_taps(ox, inW, tx, wx);
  const float* s = src + (size_t)c * inH * inW;
  float acc = 0.f;
#pragma unroll
  for (int a = 0; a < 4; ++a) {
    float row = 0.f;
#pragma unroll
    for (int b = 0; b < 4; ++b) row += wx[b] * s[(size_t)ty[a] * inW + tx[b]];
    acc += wy[a] * row;
  }
  dst[idx] = acc;
}

// ---- laplacian: lap = x - up2(down_x)
__global__ __launch_bounds__(256) void lap_k(const float* __restrict__ x,
                                             const float* __restrict__ down_x,
                                             float* __restrict__ lap) {
  int idx = blockIdx.x * 256 + threadIdx.x;
  if (idx >= 6 * 512 * 512) return;
  int ox = idx & 511;
  int r = idx >> 9;
  int oy = r & 511;
  int c = r >> 9;
  int ty[4], tx[4];
  float wy[4], wx[4];
  up_taps(oy, 256, ty, wy);
  up_taps(ox, 256, tx, wx);
  const float* s = down_x + (size_t)c * 256 * 256;
  float acc = 0.f;
#pragma unroll
  for (int a = 0; a < 4; ++a) {
    float row = 0.f;
#pragma unroll
    for (int b = 0; b < 4; ++b) row += wx[b] * s[ty[a] * 256 + tx[b]];
    acc += wy[a] * row;
  }
  lap[idx] = x[idx] - acc;
}

// ---- conv 3x3 stride2 pad1: src (2,3,inH,inW) -> dst (2,64,inH/2,inW/2)
__global__ __launch_bounds__(256) void conv3s2_k(const float* __restrict__ src,
                                                 const float* __restrict__ w,
                                                 const float* __restrict__ bias,
                                                 float* __restrict__ dst,
                                                 int inH, int inW) {
  int oH = inH >> 1, oW = inW >> 1;
  int idx = blockIdx.x * 256 + threadIdx.x;
  int total = 2 * 64 * oH * oW;
  if (idx >= total) return;
  int ox = idx % oW;
  int t = idx / oW;
  int oy = t % oH;
  t /= oH;
  int co = t & 63;
  int b = t >> 6;
  const float* sb = src + (size_t)b * 3 * inH * inW;
  const float* wc = w + co * 27;
  float acc = bias[co];
#pragma unroll
  for (int ci = 0; ci < 3; ++ci) {
    const float* sc = sb + (size_t)ci * inH * inW;
#pragma unroll
    for (int ky = 0; ky < 3; ++ky) {
      int iy = 2 * oy - 1 + ky;
      if (iy < 0 || iy >= inH) continue;
#pragma unroll
      for (int kx = 0; kx < 3; ++kx) {
        int ix = 2 * ox - 1 + kx;
        if (ix < 0 || ix >= inW) continue;
        acc += wc[ci * 9 + ky * 3 + kx] * sc[(size_t)iy * inW + ix];
      }
    }
  }
  dst[idx] = acc;
}

// ---- 1x1 conv
__global__ __launch_bounds__(256) void modconv_k(const float* __restrict__ down_x,
                                                 const float* __restrict__ outd,
                                                 const float* __restrict__ mw,
                                                 const float* __restrict__ mb,
                                                 float* __restrict__ dst) {
  int idx = blockIdx.x * 256 + threadIdx.x;
  if (idx >= 2 * 3 * 65536) return;
  int p = idx & 65535;
  int r = idx >> 16;
  int co = r % 3;
  int b = r / 3;
  const float* dxb = down_x + (size_t)b * 3 * 65536;
  const float* ob = outd + (size_t)b * 3 * 65536;
  float acc = mb[co];
#pragma unroll
  for (int ci = 0; ci < 3; ++ci) acc += mw[co * 6 + ci] * dxb[ci * 65536 + p];
#pragma unroll
  for (int ci = 0; ci < 3; ++ci) acc += mw[co * 6 + 3 + ci] * ob[ci * 65536 + p];
  dst[idx] = acc;
}

// ---------------------------------------------------------------------------
// Weight pack: all 6 MLP layers into MFMA B-fragment order, bf16.
// Layout per layer: [kstep][ntile][lane 0..63][j 0..7] ; fragment element:
//   n = ntile*16 + (lane&15), k = kstep*32 + (lane>>4)*8 + j.
// Bases (elements): L0=0 (1 ks, NT=8, Ksrc=7), L1=4096, L2=20480, L3=36864,
//   L4=53248 (4 ks, NT=8, K=128), L5=69632 (4 ks, NT=6, Nsrc=81). Total 81920.
// ---------------------------------------------------------------------------
__global__ __launch_bounds__(256) void pack_w_k(
    const float* __restrict__ Win, const float* __restrict__ Wh1,
    const float* __restrict__ Wh2, const float* __restrict__ Wh3,
    const float* __restrict__ Wh4, const float* __restrict__ Wout,
    unsigned short* __restrict__ bp) {
  int idx = blockIdx.x * 256 + threadIdx.x;
  if (idx >= 81920) return;
  const float* W;
  int base, Ksrc, Nsrc, NT;
  if (idx < 4096)       { W = Win;  base = 0;     Ksrc = 7;   Nsrc = 128; NT = 8; }
  else if (idx < 20480) { W = Wh1;  base = 4096;  Ksrc = 128; Nsrc = 128; NT = 8; }
  else if (idx < 36864) { W = Wh2;  base = 20480; Ksrc = 128; Nsrc = 128; NT = 8; }
  else if (idx < 53248) { W = Wh3;  base = 36864; Ksrc = 128; Nsrc = 128; NT = 8; }
  else if (idx < 69632) { W = Wh4;  base = 53248; Ksrc = 128; Nsrc = 128; NT = 8; }
  else                  { W = Wout; base = 69632; Ksrc = 128; Nsrc = 81;  NT = 6; }
  int rel = idx - base;
  int j = rel & 7;
  int lane = (rel >> 3) & 63;
  int t = rel >> 9;
  int nt = t % NT;
  int ks = t / NT;
  int k = ks * 32 + ((lane >> 4) << 3) + j;
  int n = nt * 16 + (lane & 15);
  float v = (k < Ksrc && n < Nsrc) ? W[k * Nsrc + n] : 0.f;
  bp[idx] = f2bf(v);
}

// ---------------------------------------------------------------------------
// Fused MFMA MLP + einsum. One block = 128 px, 256 threads (4 waves).
// Wave w owns M-tiles 2w, 2w+1 (px rows 32w..32w+31), all N-tiles.
// Activations: hi/lo bf16 planes in one LDS buffer, stride 136 (pad 8).
// Layer: acc in regs (full output) -> barrier -> write back -> barrier.
// Final layer writes fp32 local_weight, stride 97 (odd -> conflict-free).
// ---------------------------------------------------------------------------
#define HS 136

template <int KS, int NT, bool LEAKY, bool FINAL>
__device__ __forceinline__ void mlp_layer(unsigned short* hhi,
                                          unsigned short* hlo, float* lwbuf,
                                          const unsigned short* __restrict__ bp,
                                          int w, int l) {
  f32x4 acc[2][NT];
#pragma unroll
  for (int mt = 0; mt < 2; ++mt)
#pragma unroll
    for (int nt = 0; nt < NT; ++nt) acc[mt][nt] = (f32x4){0.f, 0.f, 0.f, 0.f};

  const int arow = l & 15;        // px within M-tile (A fragment row)
  const int kg = (l >> 4) << 3;   // k sub-offset
#pragma unroll
  for (int ks = 0; ks < KS; ++ks) {
    bf16x8 ah[2], al[2];
#pragma unroll
    for (int mt = 0; mt < 2; ++mt) {
      int off = ((w * 2 + mt) * 16 + arow) * HS + ks * 32 + kg;
      ah[mt] = *(const bf16x8*)&hhi[off];
      al[mt] = *(const bf16x8*)&hlo[off];
    }
#pragma unroll
    for (int nt = 0; nt < NT; ++nt) {
      bf16x8 bb = *(const bf16x8*)&bp[(size_t)((ks * NT + nt) * 64 + l) * 8];
#pragma unroll
      for (int mt = 0; mt < 2; ++mt) {
        acc[mt][nt] = __builtin_amdgcn_mfma_f32_16x16x32_bf16(ah[mt], bb,
                                                              acc[mt][nt], 0, 0, 0);
        acc[mt][nt] = __builtin_amdgcn_mfma_f32_16x16x32_bf16(al[mt], bb,
                                                              acc[mt][nt], 0, 0, 0);
      }
    }
  }
  __syncthreads();  // all waves done reading h
  const int col = l & 15;
  const int rb = (l >> 4) << 2;   // C/D: row = (lane>>4)*4 + reg
#pragma unroll
  for (int mt = 0; mt < 2; ++mt) {
#pragma unroll
    for (int nt = 0; nt < NT; ++nt) {
#pragma unroll
      for (int r = 0; r < 4; ++r) {
        int px = (w * 2 + mt) * 16 + rb + r;
        int n = nt * 16 + col;
        float v = acc[mt][nt][r];
        if (LEAKY) v = v > 0.f ? v : 0.01f * v;
        if (FINAL) {
          lwbuf[px * 97 + n] = v;
        } else {
          unsigned short h = f2bf(v);
          hhi[px * HS + n] = h;
          hlo[px * HS + n] = f2bf(v - bf2f(h));
        }
      }
    }
  }
  __syncthreads();  // h (or lwbuf) ready
}

__global__ __launch_bounds__(256) void mlp_einsum_k(
    const float* __restrict__ x, const float* __restrict__ lap,
    const unsigned short* __restrict__ bp, float* __restrict__ out_full) {
  __shared__ __align__(16) unsigned char smem[69632];
  unsigned short* hhi = (unsigned short*)smem;              // 128*136*2 = 34816 B
  unsigned short* hlo = (unsigned short*)(smem + 34816);    // 34816 B
  float* lwbuf = (float*)smem;                              // 128*97*4 = 49664 B (final)

  const int tid = threadIdx.x;
  const int w = tid >> 6, l = tid & 63;
  const int pbase = blockIdx.x * 128;

  // build MLP input, k=0..31 (zero-padded beyond 7):
  // [rel_y(+-.5), rel_x(+-.5), 1, 1, lap0, lap1, lap2]
  if (tid < 128) {
    int px = tid;
    int p = pbase + px;
    int b = p >> 18, rem = p & 262143;
    int i = rem >> 9, j = rem & 511;
    for (int k = 0; k < 32; ++k) {
      hhi[px * HS + k] = 0;
      hlo[px * HS + k] = 0;
    }
    hhi[px * HS + 0] = f2bf((i & 1) ? 0.5f : -0.5f);
    hhi[px * HS + 1] = f2bf((j & 1) ? 0.5f : -0.5f);
    hhi[px * HS + 2] = f2bf(1.f);
    hhi[px * HS + 3] = f2bf(1.f);
    const float* lp = lap + (size_t)b * 786432 + rem;
#pragma unroll
    for (int c = 0; c < 3; ++c) {
      float v = lp[c * 262144];
      unsigned short h = f2bf(v);
      hhi[px * HS + 4 + c] = h;
      hlo[px * HS + 4 + c] = f2bf(v - bf2f(h));
    }
  }
  __syncthreads();

  mlp_layer<1, 8, true, false>(hhi, hlo, nullptr, bp + 0, w, l);
  mlp_layer<4, 8, true, false>(hhi, hlo, nullptr, bp + 4096, w, l);
  mlp_layer<4, 8, true, false>(hhi, hlo, nullptr, bp + 20480, w, l);
  mlp_layer<4, 8, true, false>(hhi, hlo, nullptr, bp + 36864, w, l);
  mlp_layer<4, 8, true, false>(hhi, hlo, nullptr, bp + 53248, w, l);
  mlp_layer<4, 6, false, true>(hhi, hlo, lwbuf, bp + 69632, w, l);
  // lwbuf[px*97 + n], n=0..80 valid (81..95 are zero-weight columns)

  // einsum: out[co] = sum_{c,ki,kj} xpad * lw[(c*9+ki*3+kj)*3+co]
  if (tid < 128) {
    int px = tid;
    int p = pbase + px;
    int b = p >> 18, rem = p & 262143;
    int i = rem >> 9, j = rem & 511;
    const float* xb = x + (size_t)b * 786432;
    const float* lw = lwbuf + px * 97;
    float o0 = 0.f, o1 = 0.f, o2 = 0.f;
#pragma unroll
    for (int c = 0; c < 3; ++c) {
      const float* xc = xb + (size_t)c * 262144;
#pragma unroll
      for (int ki = 0; ki < 3; ++ki) {
        int ii = i + ki - 1;
#pragma unroll
        for (int kj = 0; kj < 3; ++kj) {
          int jj = j + kj - 1;
          float pv = (ii >= 0 && ii < 512 && jj >= 0 && jj < 512)
                         ? xc[ii * 512 + jj]
                         : 0.f;
          int q3 = (c * 9 + ki * 3 + kj) * 3;
          o0 += pv * lw[q3];
          o1 += pv * lw[q3 + 1];
          o2 += pv * lw[q3 + 2];
        }
      }
    }
    float* ob = out_full + (size_t)b * 786432 + rem;
    ob[0] = o0;
    ob[262144] = o1;
    ob[2 * 262144] = o2;
  }
}

// ---------------------------------------------------------------------------
extern "C" void kernel_launch(void* const* d_in, const int* in_sizes, int n_in,
                              void* d_out, int out_size, void* d_ws,
                              size_t ws_size, hipStream_t stream) {
  const float* x = (const float*)d_in[0];
  const float* Win = (const float*)d_in[1];
  const float* Wh1 = (const float*)d_in[2];
  const float* Wh2 = (const float*)d_in[3];
  const float* Wh3 = (const float*)d_in[4];
  const float* Wh4 = (const float*)d_in[5];
  const float* Wout = (const float*)d_in[6];
  const float* fw = (const float*)d_in[7];
  const float* fb = (const float*)d_in[8];
  const float* mw = (const float*)d_in[9];
  const float* mb = (const float*)d_in[10];

  // workspace layout (floats)
  float* ws = (float*)d_ws;
  float* down_x = ws;                    // 6*256*256      = 393216
  float* lap = ws + 393216;              // 6*512*512      = 1572864
  float* out_full = ws + 1966080;        // 6*512*512      = 1572864
  float* ctmp = ws + 3538944;            // 2*64*128*128   = 2097152 (later use)
  unsigned short* bpack = (unsigned short*)ctmp;  // 81920 bf16, aliases ctmp
  // (bpack consumed by mlp_einsum_k before ctmp is written in steps 7/8)

  // output layout (floats)
  float* o_dxm = (float*)d_out;          // (2,3,256,256)  393216
  float* o_hr = o_dxm + 393216;          // (2,64,256,256) 8388608
  float* o_new = o_hr + 8388608;         // (2,64,256,256) 8388608
  float* o_ori = o_new + 8388608;        // (2,64,256,256) 8388608
  float* o_out = o_ori + 8388608;        // (2,3,256,256)  393216

  // 0. pack MLP weights to bf16 fragment order
  pack_w_k<<<320, 256, 0, stream>>>(Win, Wh1, Wh2, Wh3, Wh4, Wout, bpack);
  // 1. down_x = bicubic down2(x)
  down2_k<<<1536, 256, 0, stream>>>(x, down_x, 6, 512, 512);
  // 2. lap = x - up2(down_x)
  lap_k<<<6144, 256, 0, stream>>>(x, down_x, lap);
  // 3. MFMA MLP + einsum -> out_full (2,3,512,512)
  mlp_einsum_k<<<4096, 256, 0, stream>>>(x, lap, bpack, out_full);
  // 4. out = down2(out_full)
  down2_k<<<1536, 256, 0, stream>>>(out_full, o_out, 6, 512, 512);
  // 5. down_x_mod = 1x1 conv(cat(down_x, out))
  modconv_k<<<1536, 256, 0, stream>>>(down_x, o_out, mw, mb, o_dxm);
  // 6. hr_feature = conv3x3 s2(x)
  conv3s2_k<<<32768, 256, 0, stream>>>(x, fw, fb, o_hr, 512, 512);
  // 7. ori_lr_feature = up2(conv3x3 s2(down_x))
  conv3s2_k<<<8192, 256, 0, stream>>>(down_x, fw, fb, ctmp, 256, 256);
  up2_k<<<32768, 256, 0, stream>>>(ctmp, o_ori, 128, 128, 128);
  // 8. new_lr_feature = up2(conv3x3 s2(down_x_mod))
  conv3s2_k<<<8192, 256, 0, stream>>>(o_dxm, fw, fb, ctmp, 256, 256);
  up2_k<<<32768, 256, 0, stream>>>(ctmp, o_new, 128, 128, 128);
}

// Round 3
// 467.052 us; speedup vs baseline: 5.2662x; 1.4040x over previous
//
#include <hip/hip_runtime.h>

// ---------------------------------------------------------------------------
// LMAR model. B=2, C=3, H=W=512, down=256. Output tuple (flat concat):
//   down_x_mod (2,3,256,256) | hr_feature (2,64,256,256) |
//   new_lr_feature (2,64,256,256) | ori_lr_feature (2,64,256,256) | out (2,3,256,256)
// MLP path: bf16 MFMA 16x16x32, A = W^T (packed fragments, LDS-staged),
// B = bf16 activations, packed b64 write-back via v_cvt_pk_bf16_f32.
// ---------------------------------------------------------------------------

typedef __attribute__((ext_vector_type(8))) short bf16x8;   // 8 bf16 = 4 VGPR
typedef __attribute__((ext_vector_type(4))) float f32x4;

__device__ __forceinline__ unsigned short f2bf(float f) {
  unsigned u = __float_as_uint(f);
  u = (u + 0x7fffu + ((u >> 16) & 1u)) >> 16;  // RNE
  return (unsigned short)u;
}

// pack 2 f32 -> u32 of 2 bf16 (RNE), hw instruction
__device__ __forceinline__ unsigned cvt_pk_bf16(float a, float b) {
  unsigned r;
  asm("v_cvt_pk_bf16_f32 %0, %1, %2" : "=v"(r) : "v"(a), "v"(b));
  return r;
}

// ---- bicubic (Keys a=-0.5) tap helpers, matching jax.image.resize
// (method='bicubic', antialias=False). Interior weights sum to exactly 1.0,
// so renormalization (divide) only happens at clipped borders.

__device__ __forceinline__ void down_taps(int o, int n, int t[4], float w[4]) {
  const float wf[4] = {-0.0625f, 0.5625f, 0.5625f, -0.0625f};
  int base = 2 * o - 1;
  if (base >= 0 && base + 3 < n) {
#pragma unroll
    for (int d = 0; d < 4; ++d) { t[d] = base + d; w[d] = wf[d]; }
    return;
  }
  float s = 0.f;
#pragma unroll
  for (int d = 0; d < 4; ++d) {
    int tt = base + d;
    bool v = (tt >= 0) && (tt < n);
    t[d] = v ? tt : 0;
    w[d] = v ? wf[d] : 0.f;
    s += w[d];
  }
#pragma unroll
  for (int d = 0; d < 4; ++d) w[d] = w[d] / s;
}

__device__ __forceinline__ void up_taps(int o, int n, int t[4], float w[4]) {
  int m = o >> 1;
  float wf[4];
  int base;
  if ((o & 1) == 0) {
    base = m - 2;
    wf[0] = -0.0234375f; wf[1] = 0.2265625f;
    wf[2] = 0.8671875f;  wf[3] = -0.0703125f;
  } else {
    base = m - 1;
    wf[0] = -0.0703125f; wf[1] = 0.8671875f;
    wf[2] = 0.2265625f;  wf[3] = -0.0234375f;
  }
  if (base >= 0 && base + 3 < n) {
#pragma unroll
    for (int d = 0; d < 4; ++d) { t[d] = base + d; w[d] = wf[d]; }
    return;
  }
  float s = 0.f;
#pragma unroll
  for (int d = 0; d < 4; ++d) {
    int tt = base + d;
    bool v = (tt >= 0) && (tt < n);
    t[d] = v ? tt : 0;
    w[d] = v ? wf[d] : 0.f;
    s += w[d];
  }
#pragma unroll
  for (int d = 0; d < 4; ++d) w[d] = w[d] / s;
}

// ---- generic 2x bicubic downscale
__global__ __launch_bounds__(256) void down2_k(const float* __restrict__ src,
                                               float* __restrict__ dst,
                                               int Ct, int inH, int inW) {
  int oH = inH >> 1, oW = inW >> 1;
  int idx = blockIdx.x * 256 + threadIdx.x;
  int total = Ct * oH * oW;
  if (idx >= total) return;
  int ox = idx % oW;
  int r = idx / oW;
  int oy = r % oH;
  int c = r / oH;
  int ty[4], tx[4];
  float wy[4], wx[4];
  down_taps(oy, inH, ty, wy);
  down_taps(ox, inW, tx, wx);
  const float* s = src + (size_t)c * inH * inW;
  float acc = 0.f;
#pragma unroll
  for (int a = 0; a < 4; ++a) {
    float row = 0.f;
#pragma unroll
    for (int b = 0; b < 4; ++b) row += wx[b] * s[(size_t)ty[a] * inW + tx[b]];
    acc += wy[a] * row;
  }
  dst[idx] = acc;
}

// ---- generic 2x bicubic upscale
__global__ __launch_bounds__(256) void up2_k(const float* __restrict__ src,
                                             float* __restrict__ dst,
                                             int Ct, int inH, int inW) {
  int oH = inH * 2, oW = inW * 2;
  int idx = blockIdx.x * 256 + threadIdx.x;
  int total = Ct * oH * oW;
  if (idx >= total) return;
  int ox = idx % oW;
  int r = idx / oW;
  int oy = r % oH;
  int c = r / oH;
  int ty[4], tx[4];
  float wy[4], wx[4];
  up_taps(oy, inH, ty, wy);
  up_taps(ox, inW, tx, wx);
  const float* s = src + (size_t)c * inH * inW;
  float acc = 0.f;
#pragma unroll
  for (int a = 0; a < 4; ++a) {
    float row = 0.f;
#pragma unroll
    for (int b = 0; b < 4; ++b) row += wx[b] * s[(size_t)ty[a] * inW + tx[b]];
    acc += wy[a] * row;
  }
  dst[idx] = acc;
}

// ---- laplacian: lap = x - up2(down_x)
__global__ __launch_bounds__(256) void lap_k(const float* __restrict__ x,
                                             const float* __restrict__ down_x,
                                             float* __restrict__ lap) {
  int idx = blockIdx.x * 256 + threadIdx.x;
  if (idx >= 6 * 512 * 512) return;
  int ox = idx & 511;
  int r = idx >> 9;
  int oy = r & 511;
  int c = r >> 9;
  int ty[4], tx[4];
  float wy[4], wx[4];
  up_taps(oy, 256, ty, wy);
  up_taps(ox, 256, tx, wx);
  const float* s = down_x + (size_t)c * 256 * 256;
  float acc = 0.f;
#pragma unroll
  for (int a = 0; a < 4; ++a) {
    float row = 0.f;
#pragma unroll
    for (int b = 0; b < 4; ++b) row += wx[b] * s[ty[a] * 256 + tx[b]];
    acc += wy[a] * row;
  }
  lap[idx] = x[idx] - acc;
}

// ---- conv 3x3 stride2 pad1: src (2,3,inH,inW) -> dst (2,64,inH/2,inW/2)
// With stride 2 / pad 1 / k3, only oy==0 or ox==0 touch the border.
__global__ __launch_bounds__(256) void conv3s2_k(const float* __restrict__ src,
                                                 const float* __restrict__ w,
                                                 const float* __restrict__ bias,
                                                 float* __restrict__ dst,
                                                 int inH, int inW) {
  int oH = inH >> 1, oW = inW >> 1;
  int idx = blockIdx.x * 256 + threadIdx.x;
  int total = 2 * 64 * oH * oW;
  if (idx >= total) return;
  int ox = idx % oW;
  int t = idx / oW;
  int oy = t % oH;
  t /= oH;
  int co = t & 63;
  int b = t >> 6;
  const float* sb = src + (size_t)b * 3 * inH * inW;
  const float* wc = w + co * 27;
  float acc = bias[co];
  if (oy > 0 && ox > 0) {
    const float* p = sb + (size_t)(2 * oy - 1) * inW + (2 * ox - 1);
#pragma unroll
    for (int ci = 0; ci < 3; ++ci) {
      const float* sc = p + (size_t)ci * inH * inW;
#pragma unroll
      for (int ky = 0; ky < 3; ++ky)
#pragma unroll
        for (int kx = 0; kx < 3; ++kx)
          acc += wc[ci * 9 + ky * 3 + kx] * sc[(size_t)ky * inW + kx];
    }
  } else {
#pragma unroll
    for (int ci = 0; ci < 3; ++ci) {
      const float* sc = sb + (size_t)ci * inH * inW;
#pragma unroll
      for (int ky = 0; ky < 3; ++ky) {
        int iy = 2 * oy - 1 + ky;
        if (iy < 0) continue;
#pragma unroll
        for (int kx = 0; kx < 3; ++kx) {
          int ix = 2 * ox - 1 + kx;
          if (ix < 0) continue;
          acc += wc[ci * 9 + ky * 3 + kx] * sc[(size_t)iy * inW + ix];
        }
      }
    }
  }
  dst[idx] = acc;
}

// ---- 1x1 conv
__global__ __launch_bounds__(256) void modconv_k(const float* __restrict__ down_x,
                                                 const float* __restrict__ outd,
                                                 const float* __restrict__ mw,
                                                 const float* __restrict__ mb,
                                                 float* __restrict__ dst) {
  int idx = blockIdx.x * 256 + threadIdx.x;
  if (idx >= 2 * 3 * 65536) return;
  int p = idx & 65535;
  int r = idx >> 16;
  int co = r % 3;
  int b = r / 3;
  const float* dxb = down_x + (size_t)b * 3 * 65536;
  const float* ob = outd + (size_t)b * 3 * 65536;
  float acc = mb[co];
#pragma unroll
  for (int ci = 0; ci < 3; ++ci) acc += mw[co * 6 + ci] * dxb[ci * 65536 + p];
#pragma unroll
  for (int ci = 0; ci < 3; ++ci) acc += mw[co * 6 + 3 + ci] * ob[ci * 65536 + p];
  dst[idx] = acc;
}

// ---------------------------------------------------------------------------
// Weight pack (unchanged): fragment element  n = nt*16 + (lane&15),
// k = ks*32 + (lane>>4)*8 + j. Read as A-fragments of W^T (A/B layouts are
// symmetric), giving D[n][px] in the MLP kernel.
// Bases (elements): L0=0, L1=4096, L2=20480, L3=36864, L4=53248, L5=69632.
// ---------------------------------------------------------------------------
__global__ __launch_bounds__(256) void pack_w_k(
    const float* __restrict__ Win, const float* __restrict__ Wh1,
    const float* __restrict__ Wh2, const float* __restrict__ Wh3,
    const float* __restrict__ Wh4, const float* __restrict__ Wout,
    unsigned short* __restrict__ bp) {
  int idx = blockIdx.x * 256 + threadIdx.x;
  if (idx >= 81920) return;
  const float* W;
  int base, Ksrc, Nsrc, NT;
  if (idx < 4096)       { W = Win;  base = 0;     Ksrc = 7;   Nsrc = 128; NT = 8; }
  else if (idx < 20480) { W = Wh1;  base = 4096;  Ksrc = 128; Nsrc = 128; NT = 8; }
  else if (idx < 36864) { W = Wh2;  base = 20480; Ksrc = 128; Nsrc = 128; NT = 8; }
  else if (idx < 53248) { W = Wh3;  base = 36864; Ksrc = 128; Nsrc = 128; NT = 8; }
  else if (idx < 69632) { W = Wh4;  base = 53248; Ksrc = 128; Nsrc = 128; NT = 8; }
  else                  { W = Wout; base = 69632; Ksrc = 128; Nsrc = 81;  NT = 6; }
  int rel = idx - base;
  int j = rel & 7;
  int lane = (rel >> 3) & 63;
  int t = rel >> 9;
  int nt = t % NT;
  int ks = t / NT;
  int k = ks * 32 + ((lane >> 4) << 3) + j;
  int n = nt * 16 + (lane & 15);
  float v = (k < Ksrc && n < Nsrc) ? W[k * Nsrc + n] : 0.f;
  bp[idx] = f2bf(v);
}

// ---------------------------------------------------------------------------
// Fused MFMA MLP + einsum. One block = 128 px, 256 threads (4 waves).
// D[n][px]: A = W^T fragments (LDS-staged, 16KB chunks), B = activations
// h[px][k] (bf16, stride HS=136). Wave w owns px-tiles {2w, 2w+1}.
// C/D: px = lane&15 (col), n = (lane>>4)*4 + r (row) -> b64 packed writes.
// Final layer -> fp32 lwbuf stride 100; einsum split across all 4 waves.
// LDS: h 34816 B | wl 16384 B | (alias) lwbuf 51200 B | pbuf 1536 B = 52736.
// ---------------------------------------------------------------------------
#define HS 136
#define LWS 100

template <int KS, int MT, bool LEAKY, bool FINAL>
__device__ __forceinline__ void mlp_layer(unsigned short* h,
                                          unsigned short* wl, float* lwbuf,
                                          const unsigned short* __restrict__ bp,
                                          int w, int l, int tid) {
  f32x4 acc[2][MT];
#pragma unroll
  for (int pt = 0; pt < 2; ++pt)
#pragma unroll
    for (int mt = 0; mt < MT; ++mt) acc[pt][mt] = (f32x4){0.f, 0.f, 0.f, 0.f};

  const int prow = l & 15;       // px within tile (B fragment col)
  const int kg = (l >> 4) << 3;  // k sub-offset

#pragma unroll
  for (int kc = 0; kc < KS; kc += 2) {
    const int nk = (KS - kc) < 2 ? (KS - kc) : 2;
    // stage nk K-steps of A-fragments into LDS (reg copy, b128)
    {
      const int total16 = nk * MT * 64;  // 16B units
      const unsigned short* src = bp + (size_t)kc * MT * 512;
      for (int t16 = tid; t16 < total16; t16 += 256)
        *(uint4*)&wl[t16 * 8] = *(const uint4*)&src[t16 * 8];
    }
    __syncthreads();
#pragma unroll
    for (int kk = 0; kk < 2; ++kk) {
      if (kk >= nk) break;
      const int ks = kc + kk;
      bf16x8 bh[2];
#pragma unroll
      for (int pt = 0; pt < 2; ++pt) {
        int px = (w * 2 + pt) * 16 + prow;
        bh[pt] = *(const bf16x8*)&h[px * HS + ks * 32 + kg];
      }
#pragma unroll
      for (int mt = 0; mt < MT; ++mt) {
        bf16x8 aw = *(const bf16x8*)&wl[((kk * MT + mt) * 64 + l) * 8];
#pragma unroll
        for (int pt = 0; pt < 2; ++pt)
          acc[pt][mt] = __builtin_amdgcn_mfma_f32_16x16x32_bf16(
              aw, bh[pt], acc[pt][mt], 0, 0, 0);
      }
    }
    __syncthreads();  // wl reusable; (last iter) all h reads done
  }

  const int col = l & 15;
  const int rb = (l >> 4) << 2;
#pragma unroll
  for (int pt = 0; pt < 2; ++pt) {
    int px = (w * 2 + pt) * 16 + col;
#pragma unroll
    for (int mt = 0; mt < MT; ++mt) {
      int n0 = mt * 16 + rb;
      float v0 = acc[pt][mt][0], v1 = acc[pt][mt][1];
      float v2 = acc[pt][mt][2], v3 = acc[pt][mt][3];
      if (LEAKY) {
        v0 = fmaxf(v0, 0.01f * v0);
        v1 = fmaxf(v1, 0.01f * v1);
        v2 = fmaxf(v2, 0.01f * v2);
        v3 = fmaxf(v3, 0.01f * v3);
      }
      if (FINAL) {
        *(f32x4*)&lwbuf[px * LWS + n0] = (f32x4){v0, v1, v2, v3};
      } else {
        uint2 u;
        u.x = cvt_pk_bf16(v0, v1);
        u.y = cvt_pk_bf16(v2, v3);
        *(uint2*)&h[px * HS + n0] = u;
      }
    }
  }
  __syncthreads();
}

__global__ __launch_bounds__(256, 3) void mlp_einsum_k(
    const float* __restrict__ x, const float* __restrict__ lap,
    const unsigned short* __restrict__ bp, float* __restrict__ out_full) {
  __shared__ __align__(16) unsigned char smem[52736];
  unsigned short* h = (unsigned short*)smem;            // 128*136*2 = 34816 B
  unsigned short* wl = (unsigned short*)(smem + 34816); // 16384 B
  float* lwbuf = (float*)smem;                          // 128*100*4 = 51200 B
  float* pbuf = (float*)(smem + 51200);                 // 128*3*4 = 1536 B

  const int tid = threadIdx.x;
  const int w = tid >> 6, l = tid & 63;
  const int pbase = blockIdx.x * 128;

  // zero k=8..31 (3 uint4 per px); k=0..7 written below
  for (int q = tid; q < 384; q += 256) {
    int px = q / 3, part = q % 3 + 1;
    *(uint4*)&h[px * HS + part * 8] = (uint4){0, 0, 0, 0};
  }
  // MLP input k=0..6: [rel_y(+-.5), rel_x(+-.5), 1, 1, lap0, lap1, lap2]
  if (tid < 128) {
    int px = tid;
    int p = pbase + px;
    int b = p >> 18, rem = p & 262143;
    int i = rem >> 9, j = rem & 511;
    const float* lp = lap + (size_t)b * 786432 + rem;
    unsigned short v[8];
    v[0] = (i & 1) ? 0x3F00u : 0xBF00u;  // +-0.5
    v[1] = (j & 1) ? 0x3F00u : 0xBF00u;
    v[2] = 0x3F80u;                      // 1.0
    v[3] = 0x3F80u;
    v[4] = f2bf(lp[0]);
    v[5] = f2bf(lp[262144]);
    v[6] = f2bf(lp[2 * 262144]);
    v[7] = 0;
    *(uint4*)&h[px * HS] = *(uint4*)v;
  }
  __syncthreads();

  mlp_layer<1, 8, true, false>(h, wl, nullptr, bp + 0, w, l, tid);
  mlp_layer<4, 8, true, false>(h, wl, nullptr, bp + 4096, w, l, tid);
  mlp_layer<4, 8, true, false>(h, wl, nullptr, bp + 20480, w, l, tid);
  mlp_layer<4, 8, true, false>(h, wl, nullptr, bp + 36864, w, l, tid);
  mlp_layer<4, 8, true, false>(h, wl, nullptr, bp + 53248, w, l, tid);
  mlp_layer<4, 6, false, true>(h, wl, lwbuf, bp + 69632, w, l, tid);
  // lwbuf[px*100 + n], n=0..80 valid

  // einsum split: waves 0,1 do q=0..13; waves 2,3 do q=14..26, then combine.
  {
    int px = tid & 127, half = tid >> 7;
    int p = pbase + px;
    int b = p >> 18, rem = p & 262143;
    int i = rem >> 9, j = rem & 511;
    const float* xb = x + (size_t)b * 786432;
    const float* lw = lwbuf + px * LWS;
    float o0 = 0.f, o1 = 0.f, o2 = 0.f;
#pragma unroll
    for (int q = 0; q < 27; ++q) {
      if ((q < 14) != (half == 0)) continue;
      int c = q / 9, ki = (q % 9) / 3, kj = q % 3;
      int ii = i + ki - 1, jj = j + kj - 1;
      float pv = (ii >= 0 && ii < 512 && jj >= 0 && jj < 512)
                     ? xb[(size_t)c * 262144 + ii * 512 + jj]
                     : 0.f;
      o0 += pv * lw[q * 3];
      o1 += pv * lw[q * 3 + 1];
      o2 += pv * lw[q * 3 + 2];
    }
    if (half) {
      pbuf[px * 3] = o0;
      pbuf[px * 3 + 1] = o1;
      pbuf[px * 3 + 2] = o2;
    }
    __syncthreads();
    if (!half) {
      float* ob = out_full + (size_t)b * 786432 + rem;
      ob[0] = o0 + pbuf[px * 3];
      ob[262144] = o1 + pbuf[px * 3 + 1];
      ob[2 * 262144] = o2 + pbuf[px * 3 + 2];
    }
  }
}

// ---------------------------------------------------------------------------
extern "C" void kernel_launch(void* const* d_in, const int* in_sizes, int n_in,
                              void* d_out, int out_size, void* d_ws,
                              size_t ws_size, hipStream_t stream) {
  const float* x = (const float*)d_in[0];
  const float* Win = (const float*)d_in[1];
  const float* Wh1 = (const float*)d_in[2];
  const float* Wh2 = (const float*)d_in[3];
  const float* Wh3 = (const float*)d_in[4];
  const float* Wh4 = (const float*)d_in[5];
  const float* Wout = (const float*)d_in[6];
  const float* fw = (const float*)d_in[7];
  const float* fb = (const float*)d_in[8];
  const float* mw = (const float*)d_in[9];
  const float* mb = (const float*)d_in[10];

  // workspace layout (floats)
  float* ws = (float*)d_ws;
  float* down_x = ws;                    // 6*256*256      = 393216
  float* lap = ws + 393216;              // 6*512*512      = 1572864
  float* out_full = ws + 1966080;        // 6*512*512      = 1572864
  float* ctmp = ws + 3538944;            // 2*64*128*128   = 2097152 (later use)
  unsigned short* bpack = (unsigned short*)ctmp;  // 81920 bf16, aliases ctmp
  // (bpack consumed by mlp_einsum_k before ctmp is written in steps 7/8)

  // output layout (floats)
  float* o_dxm = (float*)d_out;          // (2,3,256,256)  393216
  float* o_hr = o_dxm + 393216;          // (2,64,256,256) 8388608
  float* o_new = o_hr + 8388608;         // (2,64,256,256) 8388608
  float* o_ori = o_new + 8388608;        // (2,64,256,256) 8388608
  float* o_out = o_ori + 8388608;        // (2,3,256,256)  393216

  // 0. pack MLP weights to bf16 fragment order
  pack_w_k<<<320, 256, 0, stream>>>(Win, Wh1, Wh2, Wh3, Wh4, Wout, bpack);
  // 1. down_x = bicubic down2(x)
  down2_k<<<1536, 256, 0, stream>>>(x, down_x, 6, 512, 512);
  // 2. lap = x - up2(down_x)
  lap_k<<<6144, 256, 0, stream>>>(x, down_x, lap);
  // 3. MFMA MLP + einsum -> out_full (2,3,512,512)
  mlp_einsum_k<<<4096, 256, 0, stream>>>(x, lap, bpack, out_full);
  // 4. out = down2(out_full)
  down2_k<<<1536, 256, 0, stream>>>(out_full, o_out, 6, 512, 512);
  // 5. down_x_mod = 1x1 conv(cat(down_x, out))
  modconv_k<<<1536, 256, 0, stream>>>(down_x, o_out, mw, mb, o_dxm);
  // 6. hr_feature = conv3x3 s2(x)
  conv3s2_k<<<32768, 256, 0, stream>>>(x, fw, fb, o_hr, 512, 512);
  // 7. ori_lr_feature = up2(conv3x3 s2(down_x))
  conv3s2_k<<<8192, 256, 0, stream>>>(down_x, fw, fb, ctmp, 256, 256);
  up2_k<<<32768, 256, 0, stream>>>(ctmp, o_ori, 128, 128, 128);
  // 8. new_lr_feature = up2(conv3x3 s2(down_x_mod))
  conv3s2_k<<<8192, 256, 0, stream>>>(o_dxm, fw, fb, ctmp, 256, 256);
  up2_k<<<32768, 256, 0, stream>>>(ctmp, o_new, 128, 128, 128);
}

// Round 6
// 344.507 us; speedup vs baseline: 7.1395x; 1.3557x over previous
//
#include <hip/hip_runtime.h>

// ---------------------------------------------------------------------------
// LMAR model. B=2, C=3, H=W=512, down=256. Output tuple (flat concat):
//   down_x_mod (2,3,256,256) | hr_feature (2,64,256,256) |
//   new_lr_feature (2,64,256,256) | ori_lr_feature (2,64,256,256) | out (2,3,256,256)
// Round 6 = round-5 resubmission (GPU timeout, never ran):
//   round-3 MLP (known good) + round-4 ancillary kernels (bisect).
// ---------------------------------------------------------------------------

typedef __attribute__((ext_vector_type(8))) short bf16x8;   // 8 bf16 = 4 VGPR
typedef __attribute__((ext_vector_type(4))) float f32x4;

__device__ __forceinline__ unsigned short f2bf(float f) {
  unsigned u = __float_as_uint(f);
  u = (u + 0x7fffu + ((u >> 16) & 1u)) >> 16;  // RNE
  return (unsigned short)u;
}
__device__ __forceinline__ float bf2f(unsigned short h) {
  return __uint_as_float(((unsigned)h) << 16);
}
__device__ __forceinline__ unsigned cvt_pk_bf16(float a, float b) {
  unsigned r;
  asm("v_cvt_pk_bf16_f32 %0, %1, %2" : "=v"(r) : "v"(a), "v"(b));
  return r;
}

// ---- bicubic (Keys a=-0.5) taps, matching jax.image.resize bicubic
// antialias=False; interior weights sum to 1 -> renorm only at borders.

__device__ __forceinline__ void down_taps(int o, int n, int t[4], float w[4]) {
  const float wf[4] = {-0.0625f, 0.5625f, 0.5625f, -0.0625f};
  int base = 2 * o - 1;
  if (base >= 0 && base + 3 < n) {
#pragma unroll
    for (int d = 0; d < 4; ++d) { t[d] = base + d; w[d] = wf[d]; }
    return;
  }
  float s = 0.f;
#pragma unroll
  for (int d = 0; d < 4; ++d) {
    int tt = base + d;
    bool v = (tt >= 0) && (tt < n);
    t[d] = v ? tt : 0;
    w[d] = v ? wf[d] : 0.f;
    s += w[d];
  }
#pragma unroll
  for (int d = 0; d < 4; ++d) w[d] = w[d] / s;
}

// weights only (for patch-based kernels); base = m-2 (even) / m-1 (odd)
__device__ __forceinline__ void up_w(int o, int n, float w[4]) {
  int m = o >> 1;
  float wf[4];
  int base;
  if ((o & 1) == 0) {
    base = m - 2;
    wf[0] = -0.0234375f; wf[1] = 0.2265625f;
    wf[2] = 0.8671875f;  wf[3] = -0.0703125f;
  } else {
    base = m - 1;
    wf[0] = -0.0703125f; wf[1] = 0.8671875f;
    wf[2] = 0.2265625f;  wf[3] = -0.0234375f;
  }
  if (base >= 0 && base + 3 < n) {
#pragma unroll
    for (int d = 0; d < 4; ++d) w[d] = wf[d];
    return;
  }
  float s = 0.f;
#pragma unroll
  for (int d = 0; d < 4; ++d) {
    int tt = base + d;
    bool v = (tt >= 0) && (tt < n);
    w[d] = v ? wf[d] : 0.f;
    s += w[d];
  }
#pragma unroll
  for (int d = 0; d < 4; ++d) w[d] = w[d] / s;
}

// ---- 2x bicubic downscale (x -> down_x)
__global__ __launch_bounds__(256) void down2_k(const float* __restrict__ src,
                                               float* __restrict__ dst,
                                               int Ct, int inH, int inW) {
  int oH = inH >> 1, oW = inW >> 1;
  int idx = blockIdx.x * 256 + threadIdx.x;
  int total = Ct * oH * oW;
  if (idx >= total) return;
  int ox = idx % oW;
  int r = idx / oW;
  int oy = r % oH;
  int c = r / oH;
  int ty[4], tx[4];
  float wy[4], wx[4];
  down_taps(oy, inH, ty, wy);
  down_taps(ox, inW, tx, wx);
  const float* s = src + (size_t)c * inH * inW;
  float acc = 0.f;
#pragma unroll
  for (int a = 0; a < 4; ++a) {
    float row = 0.f;
#pragma unroll
    for (int b = 0; b < 4; ++b) row += wx[b] * s[(size_t)ty[a] * inW + tx[b]];
    acc += wy[a] * row;
  }
  dst[idx] = acc;
}

// ---- 2x2-blocked bicubic 2x upscale core: one thread -> 2x2 outputs.
template <bool SUB>
__device__ __forceinline__ void up2x2_core(const float* __restrict__ s, int ih,
                                           int iw, int m, int n,
                                           const float* __restrict__ xs,
                                           int xstride, float* __restrict__ d,
                                           int ostride) {
  float wye[4], wyo[4], wxe[4], wxo[4];
  up_w(2 * m, ih, wye);
  up_w(2 * m + 1, ih, wyo);
  up_w(2 * n, iw, wxe);
  up_w(2 * n + 1, iw, wxo);
  float e[5], o[5];
#pragma unroll
  for (int dy = 0; dy < 5; ++dy) {
    int y = m - 2 + dy;
    float p[5];
#pragma unroll
    for (int dx = 0; dx < 5; ++dx) {
      int x = n - 2 + dx;
      p[dx] = (y >= 0 && y < ih && x >= 0 && x < iw) ? s[(size_t)y * iw + x]
                                                     : 0.f;
    }
    e[dy] = wxe[0] * p[0] + wxe[1] * p[1] + wxe[2] * p[2] + wxe[3] * p[3];
    o[dy] = wxo[0] * p[1] + wxo[1] * p[2] + wxo[2] * p[3] + wxo[3] * p[4];
  }
  float o00 = wye[0] * e[0] + wye[1] * e[1] + wye[2] * e[2] + wye[3] * e[3];
  float o01 = wye[0] * o[0] + wye[1] * o[1] + wye[2] * o[2] + wye[3] * o[3];
  float o10 = wyo[0] * e[1] + wyo[1] * e[2] + wyo[2] * e[3] + wyo[3] * e[4];
  float o11 = wyo[0] * o[1] + wyo[1] * o[2] + wyo[2] * o[3] + wyo[3] * o[4];
  if (SUB) {
    float2 x0 = *(const float2*)xs;
    float2 x1 = *(const float2*)(xs + xstride);
    o00 = x0.x - o00; o01 = x0.y - o01;
    o10 = x1.x - o10; o11 = x1.y - o11;
  }
  *(float2*)d = make_float2(o00, o01);
  *(float2*)(d + ostride) = make_float2(o10, o11);
}

// up2 of feature maps: in (C2, ih, iw) -> out (C2, 2ih, 2iw)
__global__ __launch_bounds__(256) void up2x2_k(const float* __restrict__ in,
                                               float* __restrict__ out, int C2,
                                               int ih, int iw) {
  int idx = blockIdx.x * 256 + threadIdx.x;
  int total = C2 * ih * iw;
  if (idx >= total) return;
  int n = idx % iw;
  int r = idx / iw;
  int m = r % ih;
  int c = r / ih;
  const float* s = in + (size_t)c * ih * iw;
  float* d = out + ((size_t)c * 4 * ih * iw) + (size_t)(2 * m) * (2 * iw) +
             2 * n;
  up2x2_core<false>(s, ih, iw, m, n, nullptr, 0, d, 2 * iw);
}

// lap = x - up2(down_x): down_x (6,256,256) -> lap (6,512,512)
__global__ __launch_bounds__(256) void lapup_k(const float* __restrict__ x,
                                               const float* __restrict__ dx,
                                               float* __restrict__ lap) {
  int idx = blockIdx.x * 256 + threadIdx.x;
  if (idx >= 6 * 256 * 256) return;
  int n = idx & 255;
  int r = idx >> 8;
  int m = r & 255;
  int c = r >> 8;
  const float* s = dx + (size_t)c * 65536;
  const float* xs = x + (size_t)c * 262144 + (size_t)(2 * m) * 512 + 2 * n;
  float* d = lap + (size_t)c * 262144 + (size_t)(2 * m) * 512 + 2 * n;
  up2x2_core<true>(s, 256, 256, m, n, xs, 512, d, 512);
}

// ---- fused: o_out = down2(out_full); o_dxm = 1x1conv(cat(down_x, o_out))
__global__ __launch_bounds__(256) void down2mod_k(
    const float* __restrict__ out_full, const float* __restrict__ down_x,
    const float* __restrict__ mw, const float* __restrict__ mb,
    float* __restrict__ o_out, float* __restrict__ o_dxm) {
  int idx = blockIdx.x * 256 + threadIdx.x;
  if (idx >= 131072) return;
  int p = idx & 65535, b = idx >> 16;
  int ox = p & 255, oy = p >> 8;
  int ty[4], tx[4];
  float wy[4], wx[4];
  down_taps(oy, 512, ty, wy);
  down_taps(ox, 512, tx, wx);
  const float* sb = out_full + (size_t)b * 786432;
  float o3[3];
#pragma unroll
  for (int c = 0; c < 3; ++c) {
    const float* s = sb + (size_t)c * 262144;
    float acc = 0.f;
#pragma unroll
    for (int a = 0; a < 4; ++a) {
      float row = 0.f;
#pragma unroll
      for (int bb = 0; bb < 4; ++bb) row += wx[bb] * s[ty[a] * 512 + tx[bb]];
      acc += wy[a] * row;
    }
    o3[c] = acc;
    o_out[(size_t)b * 196608 + c * 65536 + p] = acc;
  }
  const float* dxb = down_x + (size_t)b * 196608;
  float d0 = dxb[p], d1 = dxb[65536 + p], d2 = dxb[131072 + p];
#pragma unroll
  for (int co = 0; co < 3; ++co) {
    float a = mb[co] + mw[co * 6] * d0 + mw[co * 6 + 1] * d1 +
              mw[co * 6 + 2] * d2 + mw[co * 6 + 3] * o3[0] +
              mw[co * 6 + 4] * o3[1] + mw[co * 6 + 5] * o3[2];
    o_dxm[(size_t)b * 196608 + co * 65536 + p] = a;
  }
}

// ---- tiled conv 3x3 stride2 pad1: src (2,3,inH,inW) -> dst (2,64,oH,oW)
__global__ __launch_bounds__(256) void conv3s2_t(const float* __restrict__ src,
                                                 const float* __restrict__ w,
                                                 const float* __restrict__ bias,
                                                 float* __restrict__ dst,
                                                 int inH, int inW) {
  const int oH = inH >> 1, oW = inW >> 1, nxt = oW >> 6;
  int bx = blockIdx.x;
  int ox0 = (bx % nxt) << 6;
  int t2 = bx / nxt;
  int oy = t2 % oH;
  int b = t2 / oH;
  __shared__ float ls[3][3][132];  // [ci][ky][col], col = ix - (2*ox0-1)
  const int tid = threadIdx.x;
  const float* sb = src + (size_t)b * 3 * inH * inW;
  const int iy0 = 2 * oy - 1, ix0 = 2 * ox0 - 1;
  for (int q = tid; q < 3 * 3 * 129; q += 256) {
    int col = q % 129;
    int rr = q / 129;
    int ky = rr % 3, ci = rr / 3;
    int iy = iy0 + ky, ix = ix0 + col;
    float v = 0.f;
    if (iy >= 0 && iy < inH && ix >= 0 && ix < inW)
      v = sb[(size_t)ci * inH * inW + (size_t)iy * inW + ix];
    ls[ci][ky][col] = v;
  }
  __syncthreads();
  const int cg = tid >> 6, oxl = tid & 63;
  float in[27];
#pragma unroll
  for (int ci = 0; ci < 3; ++ci)
#pragma unroll
    for (int ky = 0; ky < 3; ++ky)
#pragma unroll
      for (int kx = 0; kx < 3; ++kx)
        in[ci * 9 + ky * 3 + kx] = ls[ci][ky][2 * oxl + kx];
  const int cgs = __builtin_amdgcn_readfirstlane(cg);
  float* dp = dst + ((size_t)b * 64 + cgs * 16) * oH * oW + (size_t)oy * oW +
              ox0 + oxl;
#pragma unroll
  for (int t = 0; t < 16; ++t) {
    const int co = cgs * 16 + t;
    const float* wc = w + co * 27;
    float acc = bias[co];
#pragma unroll
    for (int q = 0; q < 27; ++q) acc += wc[q] * in[q];
    dp[(size_t)t * oH * oW] = acc;
  }
}

// ---------------------------------------------------------------------------
// Weight pack (fragment order): n = nt*16 + (lane&15), k = ks*32 + (lane>>4)*8 + j.
// Bases: L0=0, L1=4096, L2=20480, L3=36864, L4=53248, L5=69632 (total 81920).
// ---------------------------------------------------------------------------
__global__ __launch_bounds__(256) void pack_w_k(
    const float* __restrict__ Win, const float* __restrict__ Wh1,
    const float* __restrict__ Wh2, const float* __restrict__ Wh3,
    const float* __restrict__ Wh4, const float* __restrict__ Wout,
    unsigned short* __restrict__ bp) {
  int idx = blockIdx.x * 256 + threadIdx.x;
  if (idx >= 81920) return;
  const float* W;
  int base, Ksrc, Nsrc, NT;
  if (idx < 4096)       { W = Win;  base = 0;     Ksrc = 7;   Nsrc = 128; NT = 8; }
  else if (idx < 20480) { W = Wh1;  base = 4096;  Ksrc = 128; Nsrc = 128; NT = 8; }
  else if (idx < 36864) { W = Wh2;  base = 20480; Ksrc = 128; Nsrc = 128; NT = 8; }
  else if (idx < 53248) { W = Wh3;  base = 36864; Ksrc = 128; Nsrc = 128; NT = 8; }
  else if (idx < 69632) { W = Wh4;  base = 53248; Ksrc = 128; Nsrc = 128; NT = 8; }
  else                  { W = Wout; base = 69632; Ksrc = 128; Nsrc = 81;  NT = 6; }
  int rel = idx - base;
  int j = rel & 7;
  int lane = (rel >> 3) & 63;
  int t = rel >> 9;
  int nt = t % NT;
  int ks = t / NT;
  int k = ks * 32 + ((lane >> 4) << 3) + j;
  int n = nt * 16 + (lane & 15);
  float v = (k < Ksrc && n < Nsrc) ? W[k * Nsrc + n] : 0.f;
  bp[idx] = f2bf(v);
}

// ---------------------------------------------------------------------------
// Fused MFMA MLP + einsum — round-3 version (known good).
// Block = 128 px, 256 threads (4 waves). Wave w owns px-tiles {2w, 2w+1},
// all n-tiles. h: bf16 [px][k] stride HS=136. Weights LDS-staged 2 K-steps.
// Final layer -> fp32 lwbuf stride 100; einsum split across wave-halves.
// LDS: h 34816 | wl 16384 = 51200; lwbuf (alias) 51200 | pbuf @51200 = 52736.
// ---------------------------------------------------------------------------
#define HS 136
#define LWS 100

template <int KS, int MT, bool LEAKY, bool FINAL>
__device__ __forceinline__ void mlp_layer(unsigned short* h,
                                          unsigned short* wl, float* lwbuf,
                                          const unsigned short* __restrict__ bp,
                                          int w, int l, int tid) {
  f32x4 acc[2][MT];
#pragma unroll
  for (int pt = 0; pt < 2; ++pt)
#pragma unroll
    for (int mt = 0; mt < MT; ++mt) acc[pt][mt] = (f32x4){0.f, 0.f, 0.f, 0.f};

  const int prow = l & 15;       // px within tile (B fragment col)
  const int kg = (l >> 4) << 3;  // k sub-offset

#pragma unroll
  for (int kc = 0; kc < KS; kc += 2) {
    const int nk = (KS - kc) < 2 ? (KS - kc) : 2;
    {  // stage nk K-steps of W fragments into LDS (reg copy, b128)
      const int total16 = nk * MT * 64;
      const unsigned short* src = bp + (size_t)kc * MT * 512;
      for (int t16 = tid; t16 < total16; t16 += 256)
        *(uint4*)&wl[t16 * 8] = *(const uint4*)&src[t16 * 8];
    }
    __syncthreads();
#pragma unroll
    for (int kk = 0; kk < 2; ++kk) {
      if (kk >= nk) break;
      const int ks = kc + kk;
      bf16x8 bh[2];
#pragma unroll
      for (int pt = 0; pt < 2; ++pt) {
        int px = (w * 2 + pt) * 16 + prow;
        bh[pt] = *(const bf16x8*)&h[px * HS + ks * 32 + kg];
      }
#pragma unroll
      for (int mt = 0; mt < MT; ++mt) {
        bf16x8 aw = *(const bf16x8*)&wl[((kk * MT + mt) * 64 + l) * 8];
#pragma unroll
        for (int pt = 0; pt < 2; ++pt)
          acc[pt][mt] = __builtin_amdgcn_mfma_f32_16x16x32_bf16(
              aw, bh[pt], acc[pt][mt], 0, 0, 0);
      }
    }
    __syncthreads();  // wl reusable; (last chunk) all h reads done
  }

  const int col = l & 15;
  const int rb = (l >> 4) << 2;
#pragma unroll
  for (int pt = 0; pt < 2; ++pt) {
    int px = (w * 2 + pt) * 16 + col;
#pragma unroll
    for (int mt = 0; mt < MT; ++mt) {
      int n0 = mt * 16 + rb;
      float v0 = acc[pt][mt][0], v1 = acc[pt][mt][1];
      float v2 = acc[pt][mt][2], v3 = acc[pt][mt][3];
      if (LEAKY) {
        v0 = fmaxf(v0, 0.01f * v0);
        v1 = fmaxf(v1, 0.01f * v1);
        v2 = fmaxf(v2, 0.01f * v2);
        v3 = fmaxf(v3, 0.01f * v3);
      }
      if (FINAL) {
        *(f32x4*)&lwbuf[px * LWS + n0] = (f32x4){v0, v1, v2, v3};
      } else {
        uint2 u;
        u.x = cvt_pk_bf16(v0, v1);
        u.y = cvt_pk_bf16(v2, v3);
        *(uint2*)&h[px * HS + n0] = u;
      }
    }
  }
  __syncthreads();
}

__global__ __launch_bounds__(256, 3) void mlp_einsum_k(
    const float* __restrict__ x, const float* __restrict__ lap,
    const unsigned short* __restrict__ bp, float* __restrict__ out_full) {
  __shared__ __align__(16) unsigned char smem[52736];
  unsigned short* h = (unsigned short*)smem;            // 128*136*2 = 34816 B
  unsigned short* wl = (unsigned short*)(smem + 34816); // 16384 B
  float* lwbuf = (float*)smem;                          // 128*100*4 = 51200 B
  float* pbuf = (float*)(smem + 51200);                 // 128*3*4 = 1536 B

  const int tid = threadIdx.x;
  const int w = tid >> 6, l = tid & 63;
  const int pbase = blockIdx.x * 128;

  // zero k=8..31 (3 uint4 per px); k=0..7 written below
  for (int q = tid; q < 384; q += 256) {
    int px = q / 3, part = q % 3 + 1;
    *(uint4*)&h[px * HS + part * 8] = (uint4){0, 0, 0, 0};
  }
  // MLP input k=0..6: [rel_y(+-.5), rel_x(+-.5), 1, 1, lap0, lap1, lap2]
  if (tid < 128) {
    int px = tid;
    int p = pbase + px;
    int b = p >> 18, rem = p & 262143;
    int i = rem >> 9, j = rem & 511;
    const float* lp = lap + (size_t)b * 786432 + rem;
    unsigned short v[8];
    v[0] = (i & 1) ? 0x3F00u : 0xBF00u;  // +-0.5
    v[1] = (j & 1) ? 0x3F00u : 0xBF00u;
    v[2] = 0x3F80u;                      // 1.0
    v[3] = 0x3F80u;
    v[4] = f2bf(lp[0]);
    v[5] = f2bf(lp[262144]);
    v[6] = f2bf(lp[2 * 262144]);
    v[7] = 0;
    *(uint4*)&h[px * HS] = *(uint4*)v;
  }
  __syncthreads();

  mlp_layer<1, 8, true, false>(h, wl, nullptr, bp + 0, w, l, tid);
  mlp_layer<4, 8, true, false>(h, wl, nullptr, bp + 4096, w, l, tid);
  mlp_layer<4, 8, true, false>(h, wl, nullptr, bp + 20480, w, l, tid);
  mlp_layer<4, 8, true, false>(h, wl, nullptr, bp + 36864, w, l, tid);
  mlp_layer<4, 8, true, false>(h, wl, nullptr, bp + 53248, w, l, tid);
  mlp_layer<4, 6, false, true>(h, wl, lwbuf, bp + 69632, w, l, tid);
  // lwbuf[px*100 + n], n=0..80 valid

  // einsum: waves 0,1 -> q=0..13; waves 2,3 -> q=14..26; combine via pbuf.
  {
    int px = tid & 127, half = tid >> 7;
    int p = pbase + px;
    int b = p >> 18, rem = p & 262143;
    int i = rem >> 9, j = rem & 511;
    const float* xb = x + (size_t)b * 786432;
    const float* lw = lwbuf + px * LWS;
    float o0 = 0.f, o1 = 0.f, o2 = 0.f;
#pragma unroll
    for (int q = 0; q < 27; ++q) {
      if ((q < 14) != (half == 0)) continue;
      int c = q / 9, ki = (q % 9) / 3, kj = q % 3;
      int ii = i + ki - 1, jj = j + kj - 1;
      float pv = (ii >= 0 && ii < 512 && jj >= 0 && jj < 512)
                     ? xb[(size_t)c * 262144 + ii * 512 + jj]
                     : 0.f;
      o0 += pv * lw[q * 3];
      o1 += pv * lw[q * 3 + 1];
      o2 += pv * lw[q * 3 + 2];
    }
    if (half) {
      pbuf[px * 3] = o0;
      pbuf[px * 3 + 1] = o1;
      pbuf[px * 3 + 2] = o2;
    }
    __syncthreads();
    if (!half) {
      float* ob = out_full + (size_t)b * 786432 + rem;
      ob[0] = o0 + pbuf[px * 3];
      ob[262144] = o1 + pbuf[px * 3 + 1];
      ob[2 * 262144] = o2 + pbuf[px * 3 + 2];
    }
  }
}

// ---------------------------------------------------------------------------
extern "C" void kernel_launch(void* const* d_in, const int* in_sizes, int n_in,
                              void* d_out, int out_size, void* d_ws,
                              size_t ws_size, hipStream_t stream) {
  const float* x = (const float*)d_in[0];
  const float* Win = (const float*)d_in[1];
  const float* Wh1 = (const float*)d_in[2];
  const float* Wh2 = (const float*)d_in[3];
  const float* Wh3 = (const float*)d_in[4];
  const float* Wh4 = (const float*)d_in[5];
  const float* Wout = (const float*)d_in[6];
  const float* fw = (const float*)d_in[7];
  const float* fb = (const float*)d_in[8];
  const float* mw = (const float*)d_in[9];
  const float* mb = (const float*)d_in[10];

  // workspace layout (floats)
  float* ws = (float*)d_ws;
  float* down_x = ws;                    // 6*256*256      = 393216
  float* lap = ws + 393216;              // 6*512*512      = 1572864
  float* out_full = ws + 1966080;        // 6*512*512      = 1572864
  float* ctmp = ws + 3538944;            // 2*64*128*128   = 2097152
  unsigned short* bpack = (unsigned short*)ctmp;  // 81920 bf16, aliases ctmp
  // (bpack consumed by mlp_einsum_k before ctmp written in steps 7/9)

  // output layout (floats)
  float* o_dxm = (float*)d_out;          // (2,3,256,256)  393216
  float* o_hr = o_dxm + 393216;          // (2,64,256,256) 8388608
  float* o_new = o_hr + 8388608;         // (2,64,256,256) 8388608
  float* o_ori = o_new + 8388608;        // (2,64,256,256) 8388608
  float* o_out = o_ori + 8388608;        // (2,3,256,256)  393216

  // 0. pack MLP weights (bf16 fragment order)
  pack_w_k<<<320, 256, 0, stream>>>(Win, Wh1, Wh2, Wh3, Wh4, Wout, bpack);
  // 1. down_x = down2(x)
  down2_k<<<1536, 256, 0, stream>>>(x, down_x, 6, 512, 512);
  // 2. lap = x - up2(down_x)   (2x2-blocked)
  lapup_k<<<1536, 256, 0, stream>>>(x, down_x, lap);
  // 3. MFMA MLP + einsum -> out_full
  mlp_einsum_k<<<4096, 256, 0, stream>>>(x, lap, bpack, out_full);
  // 4+5. o_out = down2(out_full); o_dxm = modconv(down_x, o_out)
  down2mod_k<<<512, 256, 0, stream>>>(out_full, down_x, mw, mb, o_out, o_dxm);
  // 6. hr_feature = conv3x3s2(x)
  conv3s2_t<<<2048, 256, 0, stream>>>(x, fw, fb, o_hr, 512, 512);
  // 7+8. ori_lr_feature = up2(conv3x3s2(down_x))
  conv3s2_t<<<512, 256, 0, stream>>>(down_x, fw, fb, ctmp, 256, 256);
  up2x2_k<<<8192, 256, 0, stream>>>(ctmp, o_ori, 128, 128, 128);
  // 9+10. new_lr_feature = up2(conv3x3s2(down_x_mod))
  conv3s2_t<<<512, 256, 0, stream>>>(o_dxm, fw, fb, ctmp, 256, 256);
  up2x2_k<<<8192, 256, 0, stream>>>(ctmp, o_new, 128, 128, 128);
}